// Round 20
// baseline (180.023 us; speedup 1.0000x reference)
//
#include <hip/hip_runtime.h>
#include <hip/hip_fp16.h>

typedef _Float16 f16x8 __attribute__((ext_vector_type(8)));
typedef float f32x4 __attribute__((ext_vector_type(4)));

// B=64, T=2000, E=512, D=1024, CC=32, K=31, H=128, PAD=15

__device__ __forceinline__ unsigned short f2h(float f) {
  __half h = __float2half(f);   // v_cvt_f16_f32, RNE
  return __builtin_bit_cast(unsigned short, h);
}

__device__ __forceinline__ f16x8 u4_to_f16x8(uint4 v) {
  return __builtin_bit_cast(f16x8, v);
}

__device__ __forceinline__ float fast_tanh(float x) {
  return 1.f - 2.f / (__expf(2.f * x) + 1.f);
}

// ---------------- misc prep (r11 verbatim) ----------------
__global__ __launch_bounds__(256) void prep_kernel(
    const float* __restrict__ dec_state, const float* __restrict__ W_dec,
    const float* __restrict__ b_enc, const float* __restrict__ conv_w,
    const float* __restrict__ W_att, const float* __restrict__ W_enc,
    float* __restrict__ decb, unsigned short* __restrict__ MTg,
    unsigned short* __restrict__ WTpack)
{
  const int blk = blockIdx.x, tid = threadIdx.x;
  if (blk < 32) {
    __shared__ float sd[2048];
    const int sub = tid >> 7, h = tid & 127;
    const int b = blk*2 + sub;
    for (int i = h; i < 1024; i += 128) sd[sub*1024 + i] = dec_state[b*1024 + i];
    __syncthreads();
    float acc = b_enc[h];
    #pragma unroll 8
    for (int d = 0; d < 1024; ++d) acc = fmaf(sd[sub*1024 + d], W_dec[d*128 + h], acc);
    decb[b*128 + h] = acc;
  } else if (blk < 96) {
    const int e0 = (blk - 32) * 8;
    #pragma unroll
    for (int jj = 0; jj < 4; ++jj) {
      int idx = tid + jj*256;
      int el = idx >> 7, hh = idx & 127;
      int e = e0 + el;
      int kc = e >> 6, ks = (e >> 5) & 1, lg = (e >> 3) & 3, j = e & 7;
      int nt = hh >> 4, lr = hh & 15;
      int dst = (((kc*2 + ks)*8 + nt)*64 + lg*16 + lr)*8 + j;
      WTpack[dst] = f2h(W_enc[e*128 + hh]);
    }
  } else {
    if (tid < 128) {
      const int h = tid;
      for (int k = 0; k < 31; ++k) {
        float a = 0.f;
        #pragma unroll
        for (int c = 0; c < 32; ++c) a = fmaf(conv_w[c*31 + k], W_att[c*128 + h], a);
        MTg[h*32 + k] = f2h(a);
      }
      MTg[h*32 + 31] = 0;
    }
  }
}

// ---------------- energy v5 (r19 verbatim): row-linear A staging + LDS-resident B ----------------
__global__ __launch_bounds__(512, 2) void energy_kernel(
    const float* __restrict__ enc, const float* __restrict__ prev,
    const unsigned short* __restrict__ WTpack, const unsigned short* __restrict__ MTg,
    const float* __restrict__ decb, const float* __restrict__ W_out,
    float* __restrict__ energy)
{
  extern __shared__ __align__(16) char smem[];
  char* sB = smem;                                          // 65536 (B half)
  char* sA = smem + 65536;                                  // 65536 ([128 rows][512B] f16)
  unsigned short* sMT = (unsigned short*)(smem + 131072);   // 8192
  float* sPrev = (float*)(smem + 139264);                   // 640
  float* sDecb = (float*)(smem + 139904);                   // 512
  float* sWout = (float*)(smem + 140416);                   // 512

  const int b  = blockIdx.y;
  const int t0 = blockIdx.x * 128;
  const int tid = threadIdx.x;
  const int wave = tid >> 6, lane = tid & 63;
  const int lr = lane & 15, lg = lane >> 4;

  const float* encB = enc + (size_t)b * (2000u*512u);

  const float* rowsrc[16];
  #pragma unroll
  for (int i = 0; i < 16; ++i) {
    int rg = t0 + wave*16 + i; if (rg > 1999) rg = 1999;
    rowsrc[i] = encB + (size_t)rg*512 + lane*4;
  }

  const uint4* wsrc = (const uint4*)WTpack;
  uint4 rb[8];
  #pragma unroll
  for (int i = 0; i < 8; ++i) rb[i] = wsrc[tid + i*512];
  uint4 mt = ((const uint4*)MTg)[tid];
  float pv = 0.f;
  if (tid < 160) {
    int tt = t0 + tid - 15;
    pv = (tt >= 0 && tt < 2000) ? prev[b*2000 + tt] : 0.f;
  }
  float dv = 0.f, wv = 0.f;
  if (tid < 128) { dv = decb[b*128 + tid]; wv = W_out[tid]; }

  float4 a0r[16];
  #pragma unroll
  for (int i = 0; i < 16; ++i) a0r[i] = *reinterpret_cast<const float4*>(rowsrc[i]);

  {
    uint4* wd = (uint4*)sB;
    #pragma unroll
    for (int i = 0; i < 8; ++i) wd[tid + i*512] = rb[i];
  }
  ((uint4*)sMT)[tid] = mt;
  if (tid < 160) sPrev[tid] = pv;
  if (tid < 128) { sDecb[tid] = dv; sWout[tid] = wv; }

  #pragma unroll
  for (int i = 0; i < 16; ++i) {
    int row = wave*16 + i;
    uint2 w2;
    w2.x = ((unsigned)f2h(a0r[i].y) << 16) | f2h(a0r[i].x);
    w2.y = ((unsigned)f2h(a0r[i].w) << 16) | f2h(a0r[i].z);
    *reinterpret_cast<uint2*>(sA + row*512 + (((lane >> 1) ^ (row & 15)) << 4) + (lane & 1)*8) = w2;
  }
  asm volatile("s_waitcnt lgkmcnt(0)" ::: "memory");
  __builtin_amdgcn_sched_barrier(0);
  __builtin_amdgcn_s_barrier();

  float4 a1r[16];
  #pragma unroll
  for (int i = 0; i < 16; ++i) a1r[i] = *reinterpret_cast<const float4*>(rowsrc[i] + 256);
  uint4 nb[8];
  #pragma unroll
  for (int i = 0; i < 8; ++i) nb[i] = wsrc[4096 + tid + i*512];
  __builtin_amdgcn_sched_barrier(0);

  f32x4 acc[8];
  #pragma unroll
  for (int i = 0; i < 8; ++i) acc[i] = (f32x4){0,0,0,0};

  const char* ar = sA + (wave*16 + lr)*512;

  #pragma unroll
  for (int kc = 0; kc < 4; ++kc) {
    f16x8 A0 = *reinterpret_cast<const f16x8*>(ar + (((kc*8 + 0 + lg) ^ lr) << 4));
    f16x8 A1 = *reinterpret_cast<const f16x8*>(ar + (((kc*8 + 4 + lg) ^ lr) << 4));
    #pragma unroll
    for (int nt = 0; nt < 8; ++nt) {
      uint4 rv = *reinterpret_cast<const uint4*>(sB + ((kc*2 + 0)*8 + nt)*1024 + lane*16);
      acc[nt] = __builtin_amdgcn_mfma_f32_16x16x32_f16(A0, u4_to_f16x8(rv), acc[nt], 0, 0, 0);
    }
    #pragma unroll
    for (int nt = 0; nt < 8; ++nt) {
      uint4 rv = *reinterpret_cast<const uint4*>(sB + ((kc*2 + 1)*8 + nt)*1024 + lane*16);
      acc[nt] = __builtin_amdgcn_mfma_f32_16x16x32_f16(A1, u4_to_f16x8(rv), acc[nt], 0, 0, 0);
    }
  }

  asm volatile("s_waitcnt lgkmcnt(0)" ::: "memory");
  __builtin_amdgcn_sched_barrier(0);
  #pragma unroll
  for (int i = 0; i < 16; ++i) {
    int row = wave*16 + i;
    uint2 w2;
    w2.x = ((unsigned)f2h(a1r[i].y) << 16) | f2h(a1r[i].x);
    w2.y = ((unsigned)f2h(a1r[i].w) << 16) | f2h(a1r[i].z);
    *reinterpret_cast<uint2*>(sA + row*512 + (((lane >> 1) ^ (row & 15)) << 4) + (lane & 1)*8) = w2;
  }
  __builtin_amdgcn_s_barrier();
  {
    uint4* wd = (uint4*)sB;
    #pragma unroll
    for (int i = 0; i < 8; ++i) wd[tid + i*512] = nb[i];
  }
  asm volatile("s_waitcnt lgkmcnt(0)" ::: "memory");
  __builtin_amdgcn_sched_barrier(0);
  __builtin_amdgcn_s_barrier();

  #pragma unroll
  for (int kcl = 0; kcl < 4; ++kcl) {
    f16x8 A0 = *reinterpret_cast<const f16x8*>(ar + (((kcl*8 + 0 + lg) ^ lr) << 4));
    f16x8 A1 = *reinterpret_cast<const f16x8*>(ar + (((kcl*8 + 4 + lg) ^ lr) << 4));
    #pragma unroll
    for (int nt = 0; nt < 8; ++nt) {
      uint4 rv = *reinterpret_cast<const uint4*>(sB + ((kcl*2 + 0)*8 + nt)*1024 + lane*16);
      acc[nt] = __builtin_amdgcn_mfma_f32_16x16x32_f16(A0, u4_to_f16x8(rv), acc[nt], 0, 0, 0);
    }
    #pragma unroll
    for (int nt = 0; nt < 8; ++nt) {
      uint4 rv = *reinterpret_cast<const uint4*>(sB + ((kcl*2 + 1)*8 + nt)*1024 + lane*16);
      acc[nt] = __builtin_amdgcn_mfma_f32_16x16x32_f16(A1, u4_to_f16x8(rv), acc[nt], 0, 0, 0);
    }
  }

  {
    f16x8 a2;
    const int pb0 = wave*16 + lr + lg*8;
    #pragma unroll
    for (int j = 0; j < 8; ++j)
      a2[j] = __builtin_bit_cast(_Float16, f2h(sPrev[pb0 + j]));
    const char* mlds = (const char*)sMT + lr*64 + lg*16;
    #pragma unroll
    for (int nt = 0; nt < 8; ++nt) {
      uint4 mv = *reinterpret_cast<const uint4*>(mlds + nt*1024);
      acc[nt] = __builtin_amdgcn_mfma_f32_16x16x32_f16(a2, u4_to_f16x8(mv), acc[nt], 0, 0, 0);
    }
  }

  {
    float es0 = 0.f, es1 = 0.f, es2 = 0.f, es3 = 0.f;
    #pragma unroll
    for (int nt = 0; nt < 8; ++nt) {
      float dh = sDecb[nt*16 + lr];
      float wo = sWout[nt*16 + lr];
      es0 += fast_tanh(acc[nt][0] + dh) * wo;
      es1 += fast_tanh(acc[nt][1] + dh) * wo;
      es2 += fast_tanh(acc[nt][2] + dh) * wo;
      es3 += fast_tanh(acc[nt][3] + dh) * wo;
    }
    #pragma unroll
    for (int off = 1; off < 16; off <<= 1) {
      es0 += __shfl_xor(es0, off, 64);
      es1 += __shfl_xor(es1, off, 64);
      es2 += __shfl_xor(es2, off, 64);
      es3 += __shfl_xor(es3, off, 64);
    }
    if (lr == 0) {
      const int t = t0 + wave*16 + lg*4;
      float ev[4] = {es0, es1, es2, es3};
      #pragma unroll
      for (int r = 0; r < 4; ++r)
        if (t + r < 2000) energy[b*2000 + t + r] = ev[r];
    }
  }
}

// ---------------- softmax over T per b -> att_w (r11 verbatim) ----------------
__global__ __launch_bounds__(256) void softmax_kernel(
    const float* __restrict__ energy, float* __restrict__ attw)
{
  const int b = blockIdx.x, tid = threadIdx.x;
  __shared__ float red[4];
  __shared__ float red2[4];
  float m = -1e30f;
  for (int i = tid; i < 2000; i += 256) m = fmaxf(m, energy[b*2000 + i]);
  #pragma unroll
  for (int off = 1; off < 64; off <<= 1) m = fmaxf(m, __shfl_xor(m, off, 64));
  if ((tid & 63) == 0) red[tid >> 6] = m;
  __syncthreads();
  m = fmaxf(fmaxf(red[0], red[1]), fmaxf(red[2], red[3]));

  float s = 0.f;
  for (int i = tid; i < 2000; i += 256) {
    float p = __expf(energy[b*2000 + i] - m);
    attw[b*2000 + i] = p;
    s += p;
  }
  #pragma unroll
  for (int off = 1; off < 64; off <<= 1) s += __shfl_xor(s, off, 64);
  if ((tid & 63) == 0) red2[tid >> 6] = s;
  __syncthreads();
  s = red2[0] + red2[1] + red2[2] + red2[3];
  float inv = 1.f / s;
  for (int i = tid; i < 2000; i += 256) attw[b*2000 + i] *= inv;
}

// ---------------- att_c partials: REVERSED scan (ping-pong vs energy's forward scan) ----------------
// L3 is 256MB, enc is 262MB: a forward scan self-evicts its front. Reversing attc's traversal
// (b 63->0, ch 15->0, t descending) leaves the FRONT of enc resident for the next replay's
// forward-scanning energy kernel, and starts attc where energy just ended (hot). Per-thread
// fp32 sum is merely reversed (~1e-7 reordering noise).
__global__ __launch_bounds__(256) void attc_partial_kernel(
    const float* __restrict__ enc, const float* __restrict__ attw,
    float* __restrict__ part)
{
  const int b = 63 - blockIdx.y, ch = 15 - blockIdx.x, tid = threadIdx.x;
  const int p = tid >> 7;
  const int e4 = (tid & 127) * 4;
  const float* encB = enc + (size_t)b * (2000u*512u);
  float a0 = 0.f, a1 = 0.f, a2 = 0.f, a3 = 0.f;
  const int tlo = ch * 125;
  #pragma unroll 2
  for (int t = tlo + 124 - p; t >= tlo; t -= 2) {
    float w = attw[b*2000 + t];
    float4 v = *reinterpret_cast<const float4*>(encB + (size_t)t*512 + e4);
    a0 = fmaf(v.x, w, a0);
    a1 = fmaf(v.y, w, a1);
    a2 = fmaf(v.z, w, a2);
    a3 = fmaf(v.w, w, a3);
  }
  float4 out = {a0, a1, a2, a3};
  *reinterpret_cast<float4*>(part + ((size_t)(b*32 + ch*2 + p))*512 + e4) = out;
}

__global__ __launch_bounds__(128) void attc_reduce_kernel(
    const float* __restrict__ part, float* __restrict__ out)
{
  const int b = blockIdx.x, e4 = threadIdx.x * 4;
  float4 s = {0.f, 0.f, 0.f, 0.f};
  #pragma unroll
  for (int c = 0; c < 32; ++c) {
    float4 v = *reinterpret_cast<const float4*>(part + ((size_t)(b*32 + c))*512 + e4);
    s.x += v.x; s.y += v.y; s.z += v.z; s.w += v.w;
  }
  *reinterpret_cast<float4*>(out + b*512 + e4) = s;
}

// ---------------- launch ----------------
extern "C" void kernel_launch(void* const* d_in, const int* in_sizes, int n_in,
                              void* d_out, int out_size, void* d_ws, size_t ws_size,
                              hipStream_t stream) {
  (void)in_sizes; (void)n_in; (void)out_size; (void)ws_size;
  const float* enc       = (const float*)d_in[0];
  // d_in[1] = text_len: unused by the reference computation
  const float* dec_state = (const float*)d_in[2];
  const float* prev      = (const float*)d_in[3];
  const float* W_enc     = (const float*)d_in[4];
  const float* b_enc     = (const float*)d_in[5];
  const float* W_dec     = (const float*)d_in[6];
  const float* W_att     = (const float*)d_in[7];
  const float* conv_w    = (const float*)d_in[8];
  const float* W_out     = (const float*)d_in[9];
  // d_in[10] = b_out: softmax-invariant, dropped

  char* ws = (char*)d_ws;
  float*          energy = (float*)(ws + 0);               // 524288
  float*          decb   = (float*)(ws + 524288);          // 32768
  unsigned short* MTg    = (unsigned short*)(ws + 557056); // 8192
  unsigned short* WTpack = (unsigned short*)(ws + 565248); // 131072
  float*          part   = (float*)(ws + 696320);          // 4194304

  float* attc = (float*)d_out;             // (64, 512)
  float* attw = (float*)d_out + 64*512;    // (64, 2000)

  const int lds_bytes = 140928;   // 64K B-half + 64K A-tile + MT + prev/dec/wout

  prep_kernel        <<<97, 256, 0, stream>>>(dec_state, W_dec, b_enc, conv_w, W_att, W_enc,
                                              decb, MTg, WTpack);
  energy_kernel      <<<dim3(16, 64), 512, lds_bytes, stream>>>(enc, prev, WTpack, MTg, decb, W_out, energy);
  softmax_kernel     <<<64, 256, 0, stream>>>(energy, attw);
  attc_partial_kernel<<<dim3(16, 64), 256, 0, stream>>>(enc, attw, part);
  attc_reduce_kernel <<<64, 128, 0, stream>>>(part, attc);
}

// Round 21
// 179.491 us; speedup vs baseline: 1.0030x; 1.0030x over previous
//
#include <hip/hip_runtime.h>
#include <hip/hip_fp16.h>

typedef _Float16 f16x8 __attribute__((ext_vector_type(8)));
typedef float f32x4 __attribute__((ext_vector_type(4)));

// B=64, T=2000, E=512, D=1024, CC=32, K=31, H=128, PAD=15

__device__ __forceinline__ unsigned short f2h(float f) {
  __half h = __float2half(f);   // v_cvt_f16_f32, RNE
  return __builtin_bit_cast(unsigned short, h);
}

__device__ __forceinline__ f16x8 u4_to_f16x8(uint4 v) {
  return __builtin_bit_cast(f16x8, v);
}

__device__ __forceinline__ float fast_tanh(float x) {
  return 1.f - 2.f / (__expf(2.f * x) + 1.f);
}

// ---------------- misc prep (r11 verbatim) ----------------
__global__ __launch_bounds__(256) void prep_kernel(
    const float* __restrict__ dec_state, const float* __restrict__ W_dec,
    const float* __restrict__ b_enc, const float* __restrict__ conv_w,
    const float* __restrict__ W_att, const float* __restrict__ W_enc,
    float* __restrict__ decb, unsigned short* __restrict__ MTg,
    unsigned short* __restrict__ WTpack)
{
  const int blk = blockIdx.x, tid = threadIdx.x;
  if (blk < 32) {
    __shared__ float sd[2048];
    const int sub = tid >> 7, h = tid & 127;
    const int b = blk*2 + sub;
    for (int i = h; i < 1024; i += 128) sd[sub*1024 + i] = dec_state[b*1024 + i];
    __syncthreads();
    float acc = b_enc[h];
    #pragma unroll 8
    for (int d = 0; d < 1024; ++d) acc = fmaf(sd[sub*1024 + d], W_dec[d*128 + h], acc);
    decb[b*128 + h] = acc;
  } else if (blk < 96) {
    const int e0 = (blk - 32) * 8;
    #pragma unroll
    for (int jj = 0; jj < 4; ++jj) {
      int idx = tid + jj*256;
      int el = idx >> 7, hh = idx & 127;
      int e = e0 + el;
      int kc = e >> 6, ks = (e >> 5) & 1, lg = (e >> 3) & 3, j = e & 7;
      int nt = hh >> 4, lr = hh & 15;
      int dst = (((kc*2 + ks)*8 + nt)*64 + lg*16 + lr)*8 + j;
      WTpack[dst] = f2h(W_enc[e*128 + hh]);
    }
  } else {
    if (tid < 128) {
      const int h = tid;
      for (int k = 0; k < 31; ++k) {
        float a = 0.f;
        #pragma unroll
        for (int c = 0; c < 32; ++c) a = fmaf(conv_w[c*31 + k], W_att[c*128 + h], a);
        MTg[h*32 + k] = f2h(a);
      }
      MTg[h*32 + 31] = 0;
    }
  }
}

// ---------------- energy v5 (r19 verbatim): row-linear A staging + LDS-resident B ----------------
__global__ __launch_bounds__(512, 2) void energy_kernel(
    const float* __restrict__ enc, const float* __restrict__ prev,
    const unsigned short* __restrict__ WTpack, const unsigned short* __restrict__ MTg,
    const float* __restrict__ decb, const float* __restrict__ W_out,
    float* __restrict__ energy)
{
  extern __shared__ __align__(16) char smem[];
  char* sB = smem;                                          // 65536 (B half)
  char* sA = smem + 65536;                                  // 65536 ([128 rows][512B] f16)
  unsigned short* sMT = (unsigned short*)(smem + 131072);   // 8192
  float* sPrev = (float*)(smem + 139264);                   // 640
  float* sDecb = (float*)(smem + 139904);                   // 512
  float* sWout = (float*)(smem + 140416);                   // 512

  const int b  = blockIdx.y;
  const int t0 = blockIdx.x * 128;
  const int tid = threadIdx.x;
  const int wave = tid >> 6, lane = tid & 63;
  const int lr = lane & 15, lg = lane >> 4;

  const float* encB = enc + (size_t)b * (2000u*512u);

  const float* rowsrc[16];
  #pragma unroll
  for (int i = 0; i < 16; ++i) {
    int rg = t0 + wave*16 + i; if (rg > 1999) rg = 1999;
    rowsrc[i] = encB + (size_t)rg*512 + lane*4;
  }

  const uint4* wsrc = (const uint4*)WTpack;
  uint4 rb[8];
  #pragma unroll
  for (int i = 0; i < 8; ++i) rb[i] = wsrc[tid + i*512];
  uint4 mt = ((const uint4*)MTg)[tid];
  float pv = 0.f;
  if (tid < 160) {
    int tt = t0 + tid - 15;
    pv = (tt >= 0 && tt < 2000) ? prev[b*2000 + tt] : 0.f;
  }
  float dv = 0.f, wv = 0.f;
  if (tid < 128) { dv = decb[b*128 + tid]; wv = W_out[tid]; }

  float4 a0r[16];
  #pragma unroll
  for (int i = 0; i < 16; ++i) a0r[i] = *reinterpret_cast<const float4*>(rowsrc[i]);

  {
    uint4* wd = (uint4*)sB;
    #pragma unroll
    for (int i = 0; i < 8; ++i) wd[tid + i*512] = rb[i];
  }
  ((uint4*)sMT)[tid] = mt;
  if (tid < 160) sPrev[tid] = pv;
  if (tid < 128) { sDecb[tid] = dv; sWout[tid] = wv; }

  #pragma unroll
  for (int i = 0; i < 16; ++i) {
    int row = wave*16 + i;
    uint2 w2;
    w2.x = ((unsigned)f2h(a0r[i].y) << 16) | f2h(a0r[i].x);
    w2.y = ((unsigned)f2h(a0r[i].w) << 16) | f2h(a0r[i].z);
    *reinterpret_cast<uint2*>(sA + row*512 + (((lane >> 1) ^ (row & 15)) << 4) + (lane & 1)*8) = w2;
  }
  asm volatile("s_waitcnt lgkmcnt(0)" ::: "memory");
  __builtin_amdgcn_sched_barrier(0);
  __builtin_amdgcn_s_barrier();

  float4 a1r[16];
  #pragma unroll
  for (int i = 0; i < 16; ++i) a1r[i] = *reinterpret_cast<const float4*>(rowsrc[i] + 256);
  uint4 nb[8];
  #pragma unroll
  for (int i = 0; i < 8; ++i) nb[i] = wsrc[4096 + tid + i*512];
  __builtin_amdgcn_sched_barrier(0);

  f32x4 acc[8];
  #pragma unroll
  for (int i = 0; i < 8; ++i) acc[i] = (f32x4){0,0,0,0};

  const char* ar = sA + (wave*16 + lr)*512;

  #pragma unroll
  for (int kc = 0; kc < 4; ++kc) {
    f16x8 A0 = *reinterpret_cast<const f16x8*>(ar + (((kc*8 + 0 + lg) ^ lr) << 4));
    f16x8 A1 = *reinterpret_cast<const f16x8*>(ar + (((kc*8 + 4 + lg) ^ lr) << 4));
    #pragma unroll
    for (int nt = 0; nt < 8; ++nt) {
      uint4 rv = *reinterpret_cast<const uint4*>(sB + ((kc*2 + 0)*8 + nt)*1024 + lane*16);
      acc[nt] = __builtin_amdgcn_mfma_f32_16x16x32_f16(A0, u4_to_f16x8(rv), acc[nt], 0, 0, 0);
    }
    #pragma unroll
    for (int nt = 0; nt < 8; ++nt) {
      uint4 rv = *reinterpret_cast<const uint4*>(sB + ((kc*2 + 1)*8 + nt)*1024 + lane*16);
      acc[nt] = __builtin_amdgcn_mfma_f32_16x16x32_f16(A1, u4_to_f16x8(rv), acc[nt], 0, 0, 0);
    }
  }

  asm volatile("s_waitcnt lgkmcnt(0)" ::: "memory");
  __builtin_amdgcn_sched_barrier(0);
  #pragma unroll
  for (int i = 0; i < 16; ++i) {
    int row = wave*16 + i;
    uint2 w2;
    w2.x = ((unsigned)f2h(a1r[i].y) << 16) | f2h(a1r[i].x);
    w2.y = ((unsigned)f2h(a1r[i].w) << 16) | f2h(a1r[i].z);
    *reinterpret_cast<uint2*>(sA + row*512 + (((lane >> 1) ^ (row & 15)) << 4) + (lane & 1)*8) = w2;
  }
  __builtin_amdgcn_s_barrier();
  {
    uint4* wd = (uint4*)sB;
    #pragma unroll
    for (int i = 0; i < 8; ++i) wd[tid + i*512] = nb[i];
  }
  asm volatile("s_waitcnt lgkmcnt(0)" ::: "memory");
  __builtin_amdgcn_sched_barrier(0);
  __builtin_amdgcn_s_barrier();

  #pragma unroll
  for (int kcl = 0; kcl < 4; ++kcl) {
    f16x8 A0 = *reinterpret_cast<const f16x8*>(ar + (((kcl*8 + 0 + lg) ^ lr) << 4));
    f16x8 A1 = *reinterpret_cast<const f16x8*>(ar + (((kcl*8 + 4 + lg) ^ lr) << 4));
    #pragma unroll
    for (int nt = 0; nt < 8; ++nt) {
      uint4 rv = *reinterpret_cast<const uint4*>(sB + ((kcl*2 + 0)*8 + nt)*1024 + lane*16);
      acc[nt] = __builtin_amdgcn_mfma_f32_16x16x32_f16(A0, u4_to_f16x8(rv), acc[nt], 0, 0, 0);
    }
    #pragma unroll
    for (int nt = 0; nt < 8; ++nt) {
      uint4 rv = *reinterpret_cast<const uint4*>(sB + ((kcl*2 + 1)*8 + nt)*1024 + lane*16);
      acc[nt] = __builtin_amdgcn_mfma_f32_16x16x32_f16(A1, u4_to_f16x8(rv), acc[nt], 0, 0, 0);
    }
  }

  {
    f16x8 a2;
    const int pb0 = wave*16 + lr + lg*8;
    #pragma unroll
    for (int j = 0; j < 8; ++j)
      a2[j] = __builtin_bit_cast(_Float16, f2h(sPrev[pb0 + j]));
    const char* mlds = (const char*)sMT + lr*64 + lg*16;
    #pragma unroll
    for (int nt = 0; nt < 8; ++nt) {
      uint4 mv = *reinterpret_cast<const uint4*>(mlds + nt*1024);
      acc[nt] = __builtin_amdgcn_mfma_f32_16x16x32_f16(a2, u4_to_f16x8(mv), acc[nt], 0, 0, 0);
    }
  }

  {
    float es0 = 0.f, es1 = 0.f, es2 = 0.f, es3 = 0.f;
    #pragma unroll
    for (int nt = 0; nt < 8; ++nt) {
      float dh = sDecb[nt*16 + lr];
      float wo = sWout[nt*16 + lr];
      es0 += fast_tanh(acc[nt][0] + dh) * wo;
      es1 += fast_tanh(acc[nt][1] + dh) * wo;
      es2 += fast_tanh(acc[nt][2] + dh) * wo;
      es3 += fast_tanh(acc[nt][3] + dh) * wo;
    }
    #pragma unroll
    for (int off = 1; off < 16; off <<= 1) {
      es0 += __shfl_xor(es0, off, 64);
      es1 += __shfl_xor(es1, off, 64);
      es2 += __shfl_xor(es2, off, 64);
      es3 += __shfl_xor(es3, off, 64);
    }
    if (lr == 0) {
      const int t = t0 + wave*16 + lg*4;
      float ev[4] = {es0, es1, es2, es3};
      #pragma unroll
      for (int r = 0; r < 4; ++r)
        if (t + r < 2000) energy[b*2000 + t + r] = ev[r];
    }
  }
}

// ---------------- softmax over T per b -> att_w (r11 verbatim) ----------------
__global__ __launch_bounds__(256) void softmax_kernel(
    const float* __restrict__ energy, float* __restrict__ attw)
{
  const int b = blockIdx.x, tid = threadIdx.x;
  __shared__ float red[4];
  __shared__ float red2[4];
  float m = -1e30f;
  for (int i = tid; i < 2000; i += 256) m = fmaxf(m, energy[b*2000 + i]);
  #pragma unroll
  for (int off = 1; off < 64; off <<= 1) m = fmaxf(m, __shfl_xor(m, off, 64));
  if ((tid & 63) == 0) red[tid >> 6] = m;
  __syncthreads();
  m = fmaxf(fmaxf(red[0], red[1]), fmaxf(red[2], red[3]));

  float s = 0.f;
  for (int i = tid; i < 2000; i += 256) {
    float p = __expf(energy[b*2000 + i] - m);
    attw[b*2000 + i] = p;
    s += p;
  }
  #pragma unroll
  for (int off = 1; off < 64; off <<= 1) s += __shfl_xor(s, off, 64);
  if ((tid & 63) == 0) red2[tid >> 6] = s;
  __syncthreads();
  s = red2[0] + red2[1] + red2[2] + red2[3];
  float inv = 1.f / s;
  for (int i = tid; i < 2000; i += 256) attw[b*2000 + i] *= inv;
}

// ---------------- att_c partials: forward scan (r19 verbatim — best measured config) ----------------
__global__ __launch_bounds__(256) void attc_partial_kernel(
    const float* __restrict__ enc, const float* __restrict__ attw,
    float* __restrict__ part)
{
  const int b = blockIdx.y, ch = blockIdx.x, tid = threadIdx.x;
  const int p = tid >> 7;
  const int e4 = (tid & 127) * 4;
  const int tstart = ch * 125 + p, tend = ch * 125 + 125;
  const float* encB = enc + (size_t)b * (2000u*512u);
  float a0 = 0.f, a1 = 0.f, a2 = 0.f, a3 = 0.f;
  #pragma unroll 2
  for (int t = tstart; t < tend; t += 2) {
    float w = attw[b*2000 + t];
    float4 v = *reinterpret_cast<const float4*>(encB + (size_t)t*512 + e4);
    a0 = fmaf(v.x, w, a0);
    a1 = fmaf(v.y, w, a1);
    a2 = fmaf(v.z, w, a2);
    a3 = fmaf(v.w, w, a3);
  }
  float4 out = {a0, a1, a2, a3};
  *reinterpret_cast<float4*>(part + ((size_t)(b*32 + ch*2 + p))*512 + e4) = out;
}

__global__ __launch_bounds__(128) void attc_reduce_kernel(
    const float* __restrict__ part, float* __restrict__ out)
{
  const int b = blockIdx.x, e4 = threadIdx.x * 4;
  float4 s = {0.f, 0.f, 0.f, 0.f};
  #pragma unroll
  for (int c = 0; c < 32; ++c) {
    float4 v = *reinterpret_cast<const float4*>(part + ((size_t)(b*32 + c))*512 + e4);
    s.x += v.x; s.y += v.y; s.z += v.z; s.w += v.w;
  }
  *reinterpret_cast<float4*>(out + b*512 + e4) = s;
}

// ---------------- launch ----------------
extern "C" void kernel_launch(void* const* d_in, const int* in_sizes, int n_in,
                              void* d_out, int out_size, void* d_ws, size_t ws_size,
                              hipStream_t stream) {
  (void)in_sizes; (void)n_in; (void)out_size; (void)ws_size;
  const float* enc       = (const float*)d_in[0];
  // d_in[1] = text_len: unused by the reference computation
  const float* dec_state = (const float*)d_in[2];
  const float* prev      = (const float*)d_in[3];
  const float* W_enc     = (const float*)d_in[4];
  const float* b_enc     = (const float*)d_in[5];
  const float* W_dec     = (const float*)d_in[6];
  const float* W_att     = (const float*)d_in[7];
  const float* conv_w    = (const float*)d_in[8];
  const float* W_out     = (const float*)d_in[9];
  // d_in[10] = b_out: softmax-invariant, dropped

  char* ws = (char*)d_ws;
  float*          energy = (float*)(ws + 0);               // 524288
  float*          decb   = (float*)(ws + 524288);          // 32768
  unsigned short* MTg    = (unsigned short*)(ws + 557056); // 8192
  unsigned short* WTpack = (unsigned short*)(ws + 565248); // 131072
  float*          part   = (float*)(ws + 696320);          // 4194304

  float* attc = (float*)d_out;             // (64, 512)
  float* attw = (float*)d_out + 64*512;    // (64, 2000)

  const int lds_bytes = 140928;   // 64K B-half + 64K A-tile + MT + prev/dec/wout

  prep_kernel        <<<97, 256, 0, stream>>>(dec_state, W_dec, b_enc, conv_w, W_att, W_enc,
                                              decb, MTg, WTpack);
  energy_kernel      <<<dim3(16, 64), 512, lds_bytes, stream>>>(enc, prev, WTpack, MTg, decb, W_out, energy);
  softmax_kernel     <<<64, 256, 0, stream>>>(energy, attw);
  attc_partial_kernel<<<dim3(16, 64), 256, 0, stream>>>(enc, attw, part);
  attc_reduce_kernel <<<64, 128, 0, stream>>>(part, attc);
}

// Round 22
// 163.294 us; speedup vs baseline: 1.1025x; 1.0992x over previous
//
#include <hip/hip_runtime.h>
#include <hip/hip_fp16.h>

typedef _Float16 f16x8 __attribute__((ext_vector_type(8)));
typedef float f32x4 __attribute__((ext_vector_type(4)));

// B=64, T=2000, E=512, D=1024, CC=32, K=31, H=128, PAD=15
// FINAL CONFIG (r19 build, best measured 155.6us; family plateau 155-180us):
//  - energy: 512thr/8 waves, row-linear A staging -> LDS f16 tile (unit^row swizzle),
//    B (W_enc^T fragment-major) fully LDS-resident per half, raw-barrier half swap,
//    conv folded into one f16 MFMA (K=32, zero-padded), fast_tanh epilogue.
//  - attc: forward streaming scan, float4/lane, 32 partials/b.
//  - all matrix math f16-in/fp32-acc; absmax pinned at 4.882812e-4 across 10 rounds.

__device__ __forceinline__ unsigned short f2h(float f) {
  __half h = __float2half(f);   // v_cvt_f16_f32, RNE
  return __builtin_bit_cast(unsigned short, h);
}

__device__ __forceinline__ f16x8 u4_to_f16x8(uint4 v) {
  return __builtin_bit_cast(f16x8, v);
}

__device__ __forceinline__ float fast_tanh(float x) {
  return 1.f - 2.f / (__expf(2.f * x) + 1.f);
}

// ---------------- misc prep ----------------
__global__ __launch_bounds__(256) void prep_kernel(
    const float* __restrict__ dec_state, const float* __restrict__ W_dec,
    const float* __restrict__ b_enc, const float* __restrict__ conv_w,
    const float* __restrict__ W_att, const float* __restrict__ W_enc,
    float* __restrict__ decb, unsigned short* __restrict__ MTg,
    unsigned short* __restrict__ WTpack)
{
  const int blk = blockIdx.x, tid = threadIdx.x;
  if (blk < 32) {
    __shared__ float sd[2048];
    const int sub = tid >> 7, h = tid & 127;
    const int b = blk*2 + sub;
    for (int i = h; i < 1024; i += 128) sd[sub*1024 + i] = dec_state[b*1024 + i];
    __syncthreads();
    float acc = b_enc[h];
    #pragma unroll 8
    for (int d = 0; d < 1024; ++d) acc = fmaf(sd[sub*1024 + d], W_dec[d*128 + h], acc);
    decb[b*128 + h] = acc;
  } else if (blk < 96) {
    const int e0 = (blk - 32) * 8;
    #pragma unroll
    for (int jj = 0; jj < 4; ++jj) {
      int idx = tid + jj*256;
      int el = idx >> 7, hh = idx & 127;
      int e = e0 + el;
      int kc = e >> 6, ks = (e >> 5) & 1, lg = (e >> 3) & 3, j = e & 7;
      int nt = hh >> 4, lr = hh & 15;
      int dst = (((kc*2 + ks)*8 + nt)*64 + lg*16 + lr)*8 + j;
      WTpack[dst] = f2h(W_enc[e*128 + hh]);
    }
  } else {
    if (tid < 128) {
      const int h = tid;
      for (int k = 0; k < 31; ++k) {
        float a = 0.f;
        #pragma unroll
        for (int c = 0; c < 32; ++c) a = fmaf(conv_w[c*31 + k], W_att[c*128 + h], a);
        MTg[h*32 + k] = f2h(a);
      }
      MTg[h*32 + 31] = 0;
    }
  }
}

// ---------------- energy: row-linear A staging + LDS-resident B ----------------
__global__ __launch_bounds__(512, 2) void energy_kernel(
    const float* __restrict__ enc, const float* __restrict__ prev,
    const unsigned short* __restrict__ WTpack, const unsigned short* __restrict__ MTg,
    const float* __restrict__ decb, const float* __restrict__ W_out,
    float* __restrict__ energy)
{
  extern __shared__ __align__(16) char smem[];
  char* sB = smem;                                          // 65536 (B half)
  char* sA = smem + 65536;                                  // 65536 ([128 rows][512B] f16)
  unsigned short* sMT = (unsigned short*)(smem + 131072);   // 8192
  float* sPrev = (float*)(smem + 139264);                   // 640
  float* sDecb = (float*)(smem + 139904);                   // 512
  float* sWout = (float*)(smem + 140416);                   // 512

  const int b  = blockIdx.y;
  const int t0 = blockIdx.x * 128;
  const int tid = threadIdx.x;
  const int wave = tid >> 6, lane = tid & 63;
  const int lr = lane & 15, lg = lane >> 4;

  const float* encB = enc + (size_t)b * (2000u*512u);

  const float* rowsrc[16];
  #pragma unroll
  for (int i = 0; i < 16; ++i) {
    int rg = t0 + wave*16 + i; if (rg > 1999) rg = 1999;
    rowsrc[i] = encB + (size_t)rg*512 + lane*4;
  }

  const uint4* wsrc = (const uint4*)WTpack;
  uint4 rb[8];
  #pragma unroll
  for (int i = 0; i < 8; ++i) rb[i] = wsrc[tid + i*512];
  uint4 mt = ((const uint4*)MTg)[tid];
  float pv = 0.f;
  if (tid < 160) {
    int tt = t0 + tid - 15;
    pv = (tt >= 0 && tt < 2000) ? prev[b*2000 + tt] : 0.f;
  }
  float dv = 0.f, wv = 0.f;
  if (tid < 128) { dv = decb[b*128 + tid]; wv = W_out[tid]; }

  float4 a0r[16];
  #pragma unroll
  for (int i = 0; i < 16; ++i) a0r[i] = *reinterpret_cast<const float4*>(rowsrc[i]);

  {
    uint4* wd = (uint4*)sB;
    #pragma unroll
    for (int i = 0; i < 8; ++i) wd[tid + i*512] = rb[i];
  }
  ((uint4*)sMT)[tid] = mt;
  if (tid < 160) sPrev[tid] = pv;
  if (tid < 128) { sDecb[tid] = dv; sWout[tid] = wv; }

  #pragma unroll
  for (int i = 0; i < 16; ++i) {
    int row = wave*16 + i;
    uint2 w2;
    w2.x = ((unsigned)f2h(a0r[i].y) << 16) | f2h(a0r[i].x);
    w2.y = ((unsigned)f2h(a0r[i].w) << 16) | f2h(a0r[i].z);
    *reinterpret_cast<uint2*>(sA + row*512 + (((lane >> 1) ^ (row & 15)) << 4) + (lane & 1)*8) = w2;
  }
  asm volatile("s_waitcnt lgkmcnt(0)" ::: "memory");
  __builtin_amdgcn_sched_barrier(0);
  __builtin_amdgcn_s_barrier();

  float4 a1r[16];
  #pragma unroll
  for (int i = 0; i < 16; ++i) a1r[i] = *reinterpret_cast<const float4*>(rowsrc[i] + 256);
  uint4 nb[8];
  #pragma unroll
  for (int i = 0; i < 8; ++i) nb[i] = wsrc[4096 + tid + i*512];
  __builtin_amdgcn_sched_barrier(0);

  f32x4 acc[8];
  #pragma unroll
  for (int i = 0; i < 8; ++i) acc[i] = (f32x4){0,0,0,0};

  const char* ar = sA + (wave*16 + lr)*512;

  #pragma unroll
  for (int kc = 0; kc < 4; ++kc) {
    f16x8 A0 = *reinterpret_cast<const f16x8*>(ar + (((kc*8 + 0 + lg) ^ lr) << 4));
    f16x8 A1 = *reinterpret_cast<const f16x8*>(ar + (((kc*8 + 4 + lg) ^ lr) << 4));
    #pragma unroll
    for (int nt = 0; nt < 8; ++nt) {
      uint4 rv = *reinterpret_cast<const uint4*>(sB + ((kc*2 + 0)*8 + nt)*1024 + lane*16);
      acc[nt] = __builtin_amdgcn_mfma_f32_16x16x32_f16(A0, u4_to_f16x8(rv), acc[nt], 0, 0, 0);
    }
    #pragma unroll
    for (int nt = 0; nt < 8; ++nt) {
      uint4 rv = *reinterpret_cast<const uint4*>(sB + ((kc*2 + 1)*8 + nt)*1024 + lane*16);
      acc[nt] = __builtin_amdgcn_mfma_f32_16x16x32_f16(A1, u4_to_f16x8(rv), acc[nt], 0, 0, 0);
    }
  }

  asm volatile("s_waitcnt lgkmcnt(0)" ::: "memory");
  __builtin_amdgcn_sched_barrier(0);
  #pragma unroll
  for (int i = 0; i < 16; ++i) {
    int row = wave*16 + i;
    uint2 w2;
    w2.x = ((unsigned)f2h(a1r[i].y) << 16) | f2h(a1r[i].x);
    w2.y = ((unsigned)f2h(a1r[i].w) << 16) | f2h(a1r[i].z);
    *reinterpret_cast<uint2*>(sA + row*512 + (((lane >> 1) ^ (row & 15)) << 4) + (lane & 1)*8) = w2;
  }
  __builtin_amdgcn_s_barrier();
  {
    uint4* wd = (uint4*)sB;
    #pragma unroll
    for (int i = 0; i < 8; ++i) wd[tid + i*512] = nb[i];
  }
  asm volatile("s_waitcnt lgkmcnt(0)" ::: "memory");
  __builtin_amdgcn_sched_barrier(0);
  __builtin_amdgcn_s_barrier();

  #pragma unroll
  for (int kcl = 0; kcl < 4; ++kcl) {
    f16x8 A0 = *reinterpret_cast<const f16x8*>(ar + (((kcl*8 + 0 + lg) ^ lr) << 4));
    f16x8 A1 = *reinterpret_cast<const f16x8*>(ar + (((kcl*8 + 4 + lg) ^ lr) << 4));
    #pragma unroll
    for (int nt = 0; nt < 8; ++nt) {
      uint4 rv = *reinterpret_cast<const uint4*>(sB + ((kcl*2 + 0)*8 + nt)*1024 + lane*16);
      acc[nt] = __builtin_amdgcn_mfma_f32_16x16x32_f16(A0, u4_to_f16x8(rv), acc[nt], 0, 0, 0);
    }
    #pragma unroll
    for (int nt = 0; nt < 8; ++nt) {
      uint4 rv = *reinterpret_cast<const uint4*>(sB + ((kcl*2 + 1)*8 + nt)*1024 + lane*16);
      acc[nt] = __builtin_amdgcn_mfma_f32_16x16x32_f16(A1, u4_to_f16x8(rv), acc[nt], 0, 0, 0);
    }
  }

  {
    f16x8 a2;
    const int pb0 = wave*16 + lr + lg*8;
    #pragma unroll
    for (int j = 0; j < 8; ++j)
      a2[j] = __builtin_bit_cast(_Float16, f2h(sPrev[pb0 + j]));
    const char* mlds = (const char*)sMT + lr*64 + lg*16;
    #pragma unroll
    for (int nt = 0; nt < 8; ++nt) {
      uint4 mv = *reinterpret_cast<const uint4*>(mlds + nt*1024);
      acc[nt] = __builtin_amdgcn_mfma_f32_16x16x32_f16(a2, u4_to_f16x8(mv), acc[nt], 0, 0, 0);
    }
  }

  {
    float es0 = 0.f, es1 = 0.f, es2 = 0.f, es3 = 0.f;
    #pragma unroll
    for (int nt = 0; nt < 8; ++nt) {
      float dh = sDecb[nt*16 + lr];
      float wo = sWout[nt*16 + lr];
      es0 += fast_tanh(acc[nt][0] + dh) * wo;
      es1 += fast_tanh(acc[nt][1] + dh) * wo;
      es2 += fast_tanh(acc[nt][2] + dh) * wo;
      es3 += fast_tanh(acc[nt][3] + dh) * wo;
    }
    #pragma unroll
    for (int off = 1; off < 16; off <<= 1) {
      es0 += __shfl_xor(es0, off, 64);
      es1 += __shfl_xor(es1, off, 64);
      es2 += __shfl_xor(es2, off, 64);
      es3 += __shfl_xor(es3, off, 64);
    }
    if (lr == 0) {
      const int t = t0 + wave*16 + lg*4;
      float ev[4] = {es0, es1, es2, es3};
      #pragma unroll
      for (int r = 0; r < 4; ++r)
        if (t + r < 2000) energy[b*2000 + t + r] = ev[r];
    }
  }
}

// ---------------- softmax over T per b -> att_w ----------------
__global__ __launch_bounds__(256) void softmax_kernel(
    const float* __restrict__ energy, float* __restrict__ attw)
{
  const int b = blockIdx.x, tid = threadIdx.x;
  __shared__ float red[4];
  __shared__ float red2[4];
  float m = -1e30f;
  for (int i = tid; i < 2000; i += 256) m = fmaxf(m, energy[b*2000 + i]);
  #pragma unroll
  for (int off = 1; off < 64; off <<= 1) m = fmaxf(m, __shfl_xor(m, off, 64));
  if ((tid & 63) == 0) red[tid >> 6] = m;
  __syncthreads();
  m = fmaxf(fmaxf(red[0], red[1]), fmaxf(red[2], red[3]));

  float s = 0.f;
  for (int i = tid; i < 2000; i += 256) {
    float p = __expf(energy[b*2000 + i] - m);
    attw[b*2000 + i] = p;
    s += p;
  }
  #pragma unroll
  for (int off = 1; off < 64; off <<= 1) s += __shfl_xor(s, off, 64);
  if ((tid & 63) == 0) red2[tid >> 6] = s;
  __syncthreads();
  s = red2[0] + red2[1] + red2[2] + red2[3];
  float inv = 1.f / s;
  for (int i = tid; i < 2000; i += 256) attw[b*2000 + i] *= inv;
}

// ---------------- att_c partials: forward streaming scan ----------------
__global__ __launch_bounds__(256) void attc_partial_kernel(
    const float* __restrict__ enc, const float* __restrict__ attw,
    float* __restrict__ part)
{
  const int b = blockIdx.y, ch = blockIdx.x, tid = threadIdx.x;
  const int p = tid >> 7;
  const int e4 = (tid & 127) * 4;
  const int tstart = ch * 125 + p, tend = ch * 125 + 125;
  const float* encB = enc + (size_t)b * (2000u*512u);
  float a0 = 0.f, a1 = 0.f, a2 = 0.f, a3 = 0.f;
  #pragma unroll 2
  for (int t = tstart; t < tend; t += 2) {
    float w = attw[b*2000 + t];
    float4 v = *reinterpret_cast<const float4*>(encB + (size_t)t*512 + e4);
    a0 = fmaf(v.x, w, a0);
    a1 = fmaf(v.y, w, a1);
    a2 = fmaf(v.z, w, a2);
    a3 = fmaf(v.w, w, a3);
  }
  float4 out = {a0, a1, a2, a3};
  *reinterpret_cast<float4*>(part + ((size_t)(b*32 + ch*2 + p))*512 + e4) = out;
}

__global__ __launch_bounds__(128) void attc_reduce_kernel(
    const float* __restrict__ part, float* __restrict__ out)
{
  const int b = blockIdx.x, e4 = threadIdx.x * 4;
  float4 s = {0.f, 0.f, 0.f, 0.f};
  #pragma unroll
  for (int c = 0; c < 32; ++c) {
    float4 v = *reinterpret_cast<const float4*>(part + ((size_t)(b*32 + c))*512 + e4);
    s.x += v.x; s.y += v.y; s.z += v.z; s.w += v.w;
  }
  *reinterpret_cast<float4*>(out + b*512 + e4) = s;
}

// ---------------- launch ----------------
extern "C" void kernel_launch(void* const* d_in, const int* in_sizes, int n_in,
                              void* d_out, int out_size, void* d_ws, size_t ws_size,
                              hipStream_t stream) {
  (void)in_sizes; (void)n_in; (void)out_size; (void)ws_size;
  const float* enc       = (const float*)d_in[0];
  // d_in[1] = text_len: unused by the reference computation
  const float* dec_state = (const float*)d_in[2];
  const float* prev      = (const float*)d_in[3];
  const float* W_enc     = (const float*)d_in[4];
  const float* b_enc     = (const float*)d_in[5];
  const float* W_dec     = (const float*)d_in[6];
  const float* W_att     = (const float*)d_in[7];
  const float* conv_w    = (const float*)d_in[8];
  const float* W_out     = (const float*)d_in[9];
  // d_in[10] = b_out: softmax-invariant, dropped

  char* ws = (char*)d_ws;
  float*          energy = (float*)(ws + 0);               // 524288
  float*          decb   = (float*)(ws + 524288);          // 32768
  unsigned short* MTg    = (unsigned short*)(ws + 557056); // 8192
  unsigned short* WTpack = (unsigned short*)(ws + 565248); // 131072
  float*          part   = (float*)(ws + 696320);          // 4194304

  float* attc = (float*)d_out;             // (64, 512)
  float* attw = (float*)d_out + 64*512;    // (64, 2000)

  const int lds_bytes = 140928;   // 64K B-half + 64K A-tile + MT + prev/dec/wout

  prep_kernel        <<<97, 256, 0, stream>>>(dec_state, W_dec, b_enc, conv_w, W_att, W_enc,
                                              decb, MTg, WTpack);
  energy_kernel      <<<dim3(16, 64), 512, lds_bytes, stream>>>(enc, prev, WTpack, MTg, decb, W_out, energy);
  softmax_kernel     <<<64, 256, 0, stream>>>(energy, attw);
  attc_partial_kernel<<<dim3(16, 64), 256, 0, stream>>>(enc, attw, part);
  attc_reduce_kernel <<<64, 128, 0, stream>>>(part, attc);
}